// Round 2
// baseline (86.268 us; speedup 1.0000x reference)
//
#include <hip/hip_runtime.h>
#include <hip/hip_fp16.h>
#include <cmath>

// Radon backprojection, ONE dispatch, atomic-free, workspace-free:
//   gather: one 1024-thread block (16 waves) per 32x4 pixel tile; the 8
//   wave-groups split the angle range 8 ways. Per block: stage
//   (cos,sin)*inv_dp into LDS once (tid<A), then each thread walks its
//   angle chunk reading sino directly (4x dwordx2 fp32), lerps, masks,
//   accumulates; partials reduced in LDS and committed with plain stores.
//
// R17: R16 (occupancy 50%->100%) was NEUTRAL -> gather is NOT
// latency/occupancy bound; its VALU (~2us/SIMD) and L1/L2 traffic (~2us)
// are both tiny. Remaining controllable cost is dispatch count + the pack
// stage. This round drops the fp16 pack table entirely (gather was never
// BW-bound; sino is L2-resident at 1.1MB) and fuses to a single kernel:
// -1 dispatch, -pack kernel, -1.3MB table write. fp32 path also improves
// absmax. Trig staged per-block in LDS (180 cos/sin over 1024 thr = free).
// R14 lesson stands: no atomics, block-local sync only.
// R11 lesson stands: never per-block __threadfence on MI355X.

#define AGROUPS 8

__global__ __launch_bounds__(1024, 8) void radon_fused(
    const float* __restrict__ sino,      // [4][A][P] fp32
    const float* __restrict__ thetas,
    const float* __restrict__ positions,
    float* __restrict__ out,             // [4][nn]
    int A, int P, int N, int chunk)
{
    __shared__ float red[AGROUPS][128][4];   // 16 KB
    __shared__ float2 trig_s[1024];          // 8 KB (A <= 1024)

    const int tid = threadIdx.x;

    // ---- stage trig into LDS (once per block) ----
    const float p0     = positions[0];
    const float inv_dp = 1.0f / (positions[1] - p0);
    if (tid < A) {
        float th = thetas[tid];
        trig_s[tid] = make_float2(cosf(th) * inv_dp, sinf(th) * inv_dp);
    }
    __syncthreads();

    const float q0 = -p0 * inv_dp;

    // ---- geometry: 32x4 tile; each wave covers a 16x4 window ----
    const int nn = N * N;
    const int g  = tid >> 7;           // angle group 0..7
    const int p  = tid & 127;          // tile-local pixel 0..127
    const int hf = p >> 6;
    const int l  = p & 63;
    const int lx = l & 15;
    const int ly = l >> 4;
    const int tilesx = N >> 5;
    const int bx = blockIdx.x % tilesx;
    const int by = blockIdx.x / tilesx;
    const int x  = (bx << 5) + (hf << 4) + lx;
    const int y  = (by << 2) + ly;

    const int a0 = g * chunk;
    const int a1 = min(A, a0 + chunk);

    const float half_ = (float)(N - 1) * 0.5f;
    const float cx = (float)x - half_;
    const float cy = half_ - (float)y;

    const int AP = A * P;
    const float* __restrict__ s0 = sino;
    const float* __restrict__ s1 = sino + AP;
    const float* __restrict__ s2 = sino + 2 * AP;
    const float* __restrict__ s3 = sino + 3 * AP;

    float acc0 = 0.f, acc1 = 0.f, acc2 = 0.f, acc3 = 0.f;

#pragma unroll 4
    for (int a = a0; a < a1; ++a) {
        float2 t  = trig_s[a];               // ds_read_b64, uniform broadcast
        float f   = fmaf(cx, t.x, fmaf(cy, t.y, q0));
        float i0f = floorf(f);
        float w   = f - i0f;
        int   i0  = (int)i0f;
        float m   = (i0 >= 0 && i0 <= P - 2) ? 1.0f : 0.0f;
        int   ic  = min(max(i0, 0), P - 2);
        const int off = a * P + ic;          // uniform a*P + per-lane ic

        // dword-aligned dwordx2 loads (same pattern the old pack kernel
        // used successfully on gfx950); independent, latency-hidable.
        float2 v0 = *(const float2*)(s0 + off);
        float2 v1 = *(const float2*)(s1 + off);
        float2 v2 = *(const float2*)(s2 + off);
        float2 v3 = *(const float2*)(s3 + off);

        acc0 = fmaf(m, fmaf(w, v0.y - v0.x, v0.x), acc0);
        acc1 = fmaf(m, fmaf(w, v1.y - v1.x, v1.x), acc1);
        acc2 = fmaf(m, fmaf(w, v2.y - v2.x, v2.x), acc2);
        acc3 = fmaf(m, fmaf(w, v3.y - v3.x, v3.x), acc3);
    }

    // ---- block-local reduction over the 8 angle groups ----
    red[g][p][0] = acc0;
    red[g][p][1] = acc1;
    red[g][p][2] = acc2;
    red[g][p][3] = acc3;
    __syncthreads();

    // 512 outputs (128 pixels x 4 batches); thread t < 512 owns
    // (batch b2 = t>>7, pixel p2 = t&127), sums 8 group partials.
    if (tid < 512) {
        const int b2 = tid >> 7;
        const int p2 = tid & 127;
        float s = 0.0f;
#pragma unroll
        for (int gg = 0; gg < AGROUPS; ++gg) s += red[gg][p2][b2];

        const int hf2 = p2 >> 6;
        const int l2  = p2 & 63;
        const int x2  = (bx << 5) + (hf2 << 4) + (l2 & 15);
        const int y2  = (by << 2) + (l2 >> 4);
        out[(size_t)b2 * nn + y2 * N + x2] = s;
    }
}

// Generic fallback: direct per-batch kernel (any shape).
__global__ __launch_bounds__(256) void radon_direct_kernel(
    const float* __restrict__ sino,
    const float* __restrict__ thetas,
    const float* __restrict__ positions,
    float* __restrict__ out,
    int A, int P, int N, int BC)
{
    const int nn  = N * N;
    const int pix = blockIdx.x * blockDim.x + threadIdx.x;
    if (pix >= nn) return;
    const float p0     = positions[0];
    const float inv_dp = 1.0f / (positions[1] - p0);
    const int x = pix % N;
    const int y = pix / N;
    const float half = (float)(N - 1) * 0.5f;
    const float cx = (float)x - half;
    const float cy = half - (float)y;
    for (int b = 0; b < BC; ++b) {
        float acc = 0.0f;
        for (int a = 0; a < A; ++a) {
            float th = thetas[a];
            float f  = (cx * cosf(th) + cy * sinf(th) - p0) * inv_dp;
            float i0f = floorf(f);
            int i0 = (int)i0f;
            float w = f - i0f;
            float m = (i0 >= 0 && i0 <= P - 2) ? 1.0f : 0.0f;
            int ic = min(max(i0, 0), P - 2);
            const float* row = sino + ((size_t)b * A + a) * P + ic;
            acc = fmaf(m, fmaf(w, row[1] - row[0], row[0]), acc);
        }
        out[(size_t)b * nn + pix] = acc;
    }
}

extern "C" void kernel_launch(void* const* d_in, const int* in_sizes, int n_in,
                              void* d_out, int out_size, void* d_ws, size_t ws_size,
                              hipStream_t stream) {
    const float* sino      = (const float*)d_in[0];
    const float* thetas    = (const float*)d_in[1];
    const float* positions = (const float*)d_in[2];
    float* out             = (float*)d_out;

    const int A  = in_sizes[1];               // 180
    const int P  = in_sizes[2];               // 384
    const int BC = in_sizes[0] / (A * P);     // B*C = 4
    const int N  = (int)lroundf(sqrtf((float)(out_size / BC)));
    const int nn = N * N;

    const int chunk = (A + AGROUPS - 1) / AGROUPS;

    const bool fast = (BC == 4) && (A <= 1024) && (P >= 2) && (N % 32 == 0);

    if (fast) {
        dim3 gblock(1024);
        dim3 ggat((N / 32) * (N / 4));
        radon_fused<<<ggat, gblock, 0, stream>>>(
            sino, thetas, positions, out, A, P, N, chunk);
    } else {
        dim3 block(256);
        dim3 grid((nn + 255) / 256);
        radon_direct_kernel<<<grid, block, 0, stream>>>(
            sino, thetas, positions, out, A, P, N, BC);
    }
}

// Round 3
// 71.123 us; speedup vs baseline: 1.2129x; 1.2129x over previous
//
#include <hip/hip_runtime.h>
#include <hip/hip_fp16.h>
#include <cmath>

// Radon backprojection, TWO dispatches, atomic-free:
//   1) pack: zero-padded fp16 (v[j-1],v[j]) pair table [A][PES] (4 batches
//      per 16B entry) + trig table.
//   2) gather: one 1024-thread block (16 waves) per 64x4 pixel tile; the 4
//      wave-groups split the angle range 4 ways; partials reduced in LDS
//      (one barrier, block-local only) and committed with plain stores.
//
// R18: REVERT to the R15 structure (best measured, 70.9-72.0us).
//   - R16 (AGROUPS=8, 100% occupancy) was NEUTRAL -> gather not
//     latency/occupancy-bound.
//   - R17 (fused single-dispatch, direct fp32 reads) REGRESSED +14us ->
//     4x VMEM/L1 transactions per iter beat the saved dispatch; packed
//     dwordx4 table gather is the right structure.
//   Session picture: top-5 dispatches are all the 256MiB harness poison
//   fill (~41us @ 82% HBM peak) + reset()'s memset train; pack+gather are
//   ~6us combined. Only safe shave left: skip pack stores for j>P (never
//   read by gather since j=clamp(i0,-1,P-1)+1 <= P).
// R14 lesson stands: no atomics, block-local sync only.
// R11 lesson stands: never per-block __threadfence on MI355X.

#define AGROUPS 4

typedef __fp16 half2v __attribute__((ext_vector_type(2)));

__device__ __forceinline__ half2v as_h2(unsigned u) {
    union { unsigned u; half2v h; } x; x.u = u; return x.h;
}

__global__ __launch_bounds__(256) void radon_pack(
    const float* __restrict__ sino,
    const float* __restrict__ thetas,
    const float* __restrict__ positions,
    uint4* __restrict__ packed,        // [A][PES]; entry j: (v[j-1], v[j]) x4
    float2* __restrict__ trig,         // [A+1]; trig[A].x = q0
    int A, int P, int PES, int bstride)
{
    const int gidx = blockIdx.x * 256 + threadIdx.x;
    const int a = gidx / PES;
    const int j = gidx - a * PES;
    if (a >= A) return;

    const float p0     = positions[0];
    const float inv_dp = 1.0f / (positions[1] - p0);
    if (j == 0) {
        float th = thetas[a];
        trig[a] = make_float2(cosf(th) * inv_dp, sinf(th) * inv_dp);
        if (a == 0) trig[A] = make_float2(-p0 * inv_dp, 0.0f);
    }

    if (j > P) return;                 // entries P+1..PES-1 are never read

    uint4 e = make_uint4(0, 0, 0, 0);
    if (j >= 1 && j <= P - 1) {
        const float* s = sino + (size_t)a * P + (j - 1);
        unsigned* ep = (unsigned*)&e;
#pragma unroll
        for (int b = 0; b < 4; ++b) {
            float2 v = *(const float2*)(s + (size_t)b * bstride); // dwordx2
            half2v h = __builtin_amdgcn_cvt_pkrtz(v.x, v.y);      // lo=v0 hi=v1
            union { half2v h; unsigned u; } cvt; cvt.h = h;
            ep[b] = cvt.u;
        }
    }
    packed[(size_t)a * PES + j] = e;
}

__global__ __launch_bounds__(1024) void radon_gather_red(
    const uint4* __restrict__ packed,  // [A][PES]
    const float2* __restrict__ trig,   // [A+1]
    float* __restrict__ out,           // [4][nn]
    int A, int P, int PES, int N, int chunk)
{
    __shared__ float red[AGROUPS][256][4];   // 16 KB

    const int tid = threadIdx.x;
    const int nn  = N * N;
    const int g   = tid >> 8;          // angle group 0..3
    const int p   = tid & 255;         // tile-local pixel 0..255

    // 16x4 wave tiling of the 64x4 tile.
    const int w  = p >> 6;             // wave-tile 0..3
    const int l  = p & 63;
    const int lx = l & 15;
    const int ly = l >> 4;
    const int tilesx = N >> 6;
    const int bx = blockIdx.x % tilesx;
    const int by = blockIdx.x / tilesx;
    const int x  = (bx << 6) + (w << 4) + lx;
    const int y  = (by << 2) + ly;

    const int a0 = g * chunk;
    const int a1 = min(A, a0 + chunk);

    const float half = (float)(N - 1) * 0.5f;
    const float cx = (float)x - half;
    const float cy = half - (float)y;
    const float q0 = trig[A].x;        // uniform -> s_load

    float acc0 = 0.f, acc1 = 0.f, acc2 = 0.f, acc3 = 0.f;

#pragma unroll 4
    for (int a = a0; a < a1; ++a) {
        float2 t  = trig[a];           // uniform -> s_load_dwordx2
        float f   = fmaf(cx, t.x, fmaf(cy, t.y, q0));
        float i0f = floorf(f);
        float w_  = f - i0f;
        int   i0  = (int)i0f;
        int   j   = min(max(i0, -1), P - 1) + 1;   // borders -> zero entries

        half2v w2 = __builtin_amdgcn_cvt_pkrtz(1.0f - w_, w_);   // (om, wm)
        uint4 e = packed[(size_t)a * PES + j];      // global_load_dwordx4
        acc0 = __builtin_amdgcn_fdot2(as_h2(e.x), w2, acc0, false);
        acc1 = __builtin_amdgcn_fdot2(as_h2(e.y), w2, acc1, false);
        acc2 = __builtin_amdgcn_fdot2(as_h2(e.z), w2, acc2, false);
        acc3 = __builtin_amdgcn_fdot2(as_h2(e.w), w2, acc3, false);
    }

    // ds_write_b128: this group's 4-batch partial for pixel p.
    red[g][p][0] = acc0;
    red[g][p][1] = acc1;
    red[g][p][2] = acc2;
    red[g][p][3] = acc3;
    __syncthreads();

    // Reduce phase: thread t -> (batch b2 = t>>8, pixel p2 = t&255).
    const int b2 = tid >> 8;
    const int p2 = tid & 255;
    float s = red[0][p2][b2] + red[1][p2][b2]
            + red[2][p2][b2] + red[3][p2][b2];

    const int w2_ = p2 >> 6;
    const int l2  = p2 & 63;
    const int x2  = (bx << 6) + (w2_ << 4) + (l2 & 15);
    const int y2  = (by << 2) + (l2 >> 4);
    out[(size_t)b2 * nn + y2 * N + x2] = s;
}

// Generic fallback: direct per-batch kernel (any shape).
__global__ __launch_bounds__(256) void radon_direct_kernel(
    const float* __restrict__ sino,
    const float* __restrict__ thetas,
    const float* __restrict__ positions,
    float* __restrict__ out,
    int A, int P, int N, int BC)
{
    const int nn  = N * N;
    const int pix = blockIdx.x * blockDim.x + threadIdx.x;
    if (pix >= nn) return;
    const float p0     = positions[0];
    const float inv_dp = 1.0f / (positions[1] - p0);
    const int x = pix % N;
    const int y = pix / N;
    const float half = (float)(N - 1) * 0.5f;
    const float cx = (float)x - half;
    const float cy = half - (float)y;
    for (int b = 0; b < BC; ++b) {
        float acc = 0.0f;
        for (int a = 0; a < A; ++a) {
            float th = thetas[a];
            float f  = (cx * cosf(th) + cy * sinf(th) - p0) * inv_dp;
            float i0f = floorf(f);
            int i0 = (int)i0f;
            float w = f - i0f;
            float m = (i0 >= 0 && i0 <= P - 2) ? 1.0f : 0.0f;
            int ic = min(max(i0, 0), P - 2);
            const float* row = sino + ((size_t)b * A + a) * P + ic;
            acc = fmaf(m, fmaf(w, row[1] - row[0], row[0]), acc);
        }
        out[(size_t)b * nn + pix] = acc;
    }
}

extern "C" void kernel_launch(void* const* d_in, const int* in_sizes, int n_in,
                              void* d_out, int out_size, void* d_ws, size_t ws_size,
                              hipStream_t stream) {
    const float* sino      = (const float*)d_in[0];
    const float* thetas    = (const float*)d_in[1];
    const float* positions = (const float*)d_in[2];
    float* out             = (float*)d_out;

    const int A  = in_sizes[1];               // 180
    const int P  = in_sizes[2];               // 384
    const int BC = in_sizes[0] / (A * P);     // B*C = 4
    const int N  = (int)lroundf(sqrtf((float)(out_size / BC)));
    const int nn = N * N;
    const int bstride = A * P;

    const int PES   = (P + 2 + 63) & ~63;     // padded entries per angle
    const int chunk = (A + AGROUPS - 1) / AGROUPS;

    const size_t packed_bytes = (size_t)A * PES * sizeof(uint4);
    const size_t trig_bytes   = (size_t)(A + 1) * sizeof(float2);
    const size_t need = packed_bytes + trig_bytes;

    const bool fast = (BC == 4) && (A <= 1024) && (P >= 2)
                   && (N % 64 == 0) && (ws_size >= need);

    if (fast) {
        uint4*  packed = (uint4*)d_ws;
        float2* trig   = (float2*)((char*)d_ws + packed_bytes);

        dim3 block(256);
        dim3 gpack(((unsigned)(A * PES) + 255) / 256);
        radon_pack<<<gpack, block, 0, stream>>>(
            sino, thetas, positions, packed, trig, A, P, PES, bstride);

        dim3 gblock(1024);
        dim3 ggat((N / 64) * (N / 4));
        radon_gather_red<<<ggat, gblock, 0, stream>>>(
            packed, trig, out, A, P, PES, N, chunk);
    } else {
        dim3 block(256);
        dim3 grid((nn + 255) / 256);
        radon_direct_kernel<<<grid, block, 0, stream>>>(
            sino, thetas, positions, out, A, P, N, BC);
    }
}